// Round 7
// baseline (387.210 us; speedup 1.0000x reference)
//
#include <hip/hip_runtime.h>

// Fused 1x1-conv GEMM + GroupNorm + HardTanh, MI355X (gfx950).
// Round 10: delete the y round-trip via GEMM recompute.
// History: round-4 (m97-style loop, y-store) = 368.9us PASS; round-9
// (BK=32 double-buffer + NT stores, y-store) = 377.9us PASS -> pipeline
// theory falsified (TLP already hides staging; m114 mechanism). The
// remaining structural cost is the y intermediate: 103MB write + 103MB
// read (~33us HBM) + a whole k_norm pass + L2/L3 pollution.
// New structure: MFMA is ~20%-utilized, so recompute is cheaper than the
// round-trip:
//   k0 (transpose+wconv)  -> k_gemm_stats (K-loop + stats-only epilogue)
//   -> k_finalize (ss)    -> k_gemm_out  (K-loop recompute + norm + clamp
//                                         + direct f32 out stores)
// K-loop reused VERBATIM from the round-9 kernel (hardware-verified).
// Stats slots bijective, out writers exclusive (slo predicate) ->
// deterministic. out stores: 16 lanes x 4B = 64B segments, 4 ni x 16
// floats = 256B contiguous per (mi,rr) row. absmax should IMPROVE
// (f16 y-quantization eliminated; only f16 input rounding remains).

#define HW    3136
#define CIN   256
#define COUT  512
#define BATCH 32
#define NG    32
#define CPG   16
#define EPS   1e-5f

typedef _Float16 f16x8 __attribute__((ext_vector_type(8)));
typedef float    f32x4 __attribute__((ext_vector_type(4)));
typedef unsigned int u32;

// async global->LDS DMA, 16B per lane; LDS dest = wave-uniform base + lane*16
__device__ __forceinline__ void gload16(const void* g, void* l) {
  __builtin_amdgcn_global_load_lds(
      (const u32 __attribute__((address_space(1)))*)g,
      (u32 __attribute__((address_space(3)))*)l, 16, 0, 0);
}

// ---------------------------------------------------------------------------
// K0: x [B][CIN][HW] f32 -> xT [B][HW][CIN] f16. 64x64 tile via fp32 LDS,
// row stride 65 dwords => <=2-way bank aliasing both phases (free per m136).
// Also converts w->f16. Unchanged from the passing round-4/9 kernels.
// ---------------------------------------------------------------------------
__global__ __launch_bounds__(256) void k0_transpose(
    const float* __restrict__ x, const float* __restrict__ w,
    _Float16* __restrict__ xT, _Float16* __restrict__ wf)
{
  __shared__ float T[64 * 65];
  const int bid = blockIdx.x;
  const int t   = threadIdx.x;
  const int b   = bid / 196;       // 49 s-tiles * 4 c-tiles
  const int r   = bid % 196;
  const int st  = r >> 2;
  const int ct  = r & 3;
  const int s0  = st * 64, c0 = ct * 64;

  const float* xb = x + ((size_t)b * CIN + c0) * HW + s0;
#pragma unroll
  for (int rr = 0; rr < 4; ++rr) {
    const int c_loc = (t >> 4) + rr * 16;
    const int s4    = (t & 15) * 4;
    const float4 v  = *(const float4*)(xb + (size_t)c_loc * HW + s4);
    T[(s4 + 0) * 65 + c_loc] = v.x;
    T[(s4 + 1) * 65 + c_loc] = v.y;
    T[(s4 + 2) * 65 + c_loc] = v.z;
    T[(s4 + 3) * 65 + c_loc] = v.w;
  }
  __syncthreads();
#pragma unroll
  for (int p = 0; p < 2; ++p) {
    const int s_loc = p * 32 + (t >> 3);
    const int cg    = (t & 7) * 8;
    f16x8 o;
#pragma unroll
    for (int j = 0; j < 8; ++j) o[j] = (_Float16)T[s_loc * 65 + cg + j];
    *(f16x8*)(xT + ((size_t)b * HW + s0 + s_loc) * CIN + c0 + cg) = o;
  }
  if (bid < (COUT * CIN) / 256) wf[bid * 256 + t] = (_Float16)w[bid * 256 + t];
}

// ---------------------------------------------------------------------------
// Shared GEMM core: C[128co x 128s] tile, BK=32, 8 K-steps, double-buffered
// LDS, 4 waves (2x2), 4x4 16x16x32 f16 MFMA tiles/wave. Verbatim the
// round-9 hardware-verified loop. __shared__ is function-static; forceinline
// into each caller kernel gives each its own 32KB allocation.
// ---------------------------------------------------------------------------
__device__ __forceinline__ void gemm_tile(
    const _Float16* __restrict__ xT, const _Float16* __restrict__ wf,
    int b, int mt, int s0, int t, f32x4 (&acc)[4][4])
{
  __shared__ __align__(16) _Float16 As[2 * 128 * 32];
  __shared__ __align__(16) _Float16 Bs[2 * 128 * 32];

  const int lane = t & 63;
  const int wid  = t >> 6;
  const int wy   = wid >> 1, wx = wid & 1;

  // staging geometry: thread covers row r=t>>2 (and r+64), chunk t&3 of a
  // 64B row; global-side chunk permutation ch = (t&3) ^ ((r>>1)&3).
  const int r_st = t >> 2;
  const int ch   = (t & 3) ^ ((r_st >> 1) & 3);

  const _Float16* xb  = xT + (size_t)b * HW * CIN;
  const _Float16* gA0 = wf + (size_t)(mt * 128 + r_st) * CIN + ch * 8;
  const _Float16* gA1 = gA0 + (size_t)64 * CIN;
  const _Float16* gB0 = xb + (size_t)(s0 + r_st) * CIN + ch * 8;
  const _Float16* gB1 = gB0 + (size_t)64 * CIN;

#define STAGE(bufi, kt_)                                                  \
  do {                                                                    \
    gload16(gA0 + (kt_) * 32, As + (bufi) * 4096 + t * 8);                \
    gload16(gA1 + (kt_) * 32, As + (bufi) * 4096 + 2048 + t * 8);         \
    gload16(gB0 + (kt_) * 32, Bs + (bufi) * 4096 + t * 8);                \
    gload16(gB1 + (kt_) * 32, Bs + (bufi) * 4096 + 2048 + t * 8);         \
  } while (0)

  STAGE(0, 0);
  __syncthreads();   // drain prologue stage

  const int c = lane >> 4;            // logical 8-half chunk of the 32-k row
#pragma unroll
  for (int kt = 0; kt < 8; ++kt) {
    const int cur = kt & 1;
    if (kt < 7) STAGE(cur ^ 1, kt + 1);   // issue next tile early

    f16x8 af[4], bfr[4];
#pragma unroll
    for (int mi = 0; mi < 4; ++mi) {
      const int m = wy * 64 + mi * 16 + (lane & 15);
      af[mi] = *(const f16x8*)(As + cur * 4096 + m * 32 +
                               ((c ^ ((m >> 1) & 3)) * 8));
    }
#pragma unroll
    for (int ni = 0; ni < 4; ++ni) {
      const int n = wx * 64 + ni * 16 + (lane & 15);
      bfr[ni] = *(const f16x8*)(Bs + cur * 4096 + n * 32 +
                                ((c ^ ((n >> 1) & 3)) * 8));
    }
#pragma unroll
    for (int mi = 0; mi < 4; ++mi)
#pragma unroll
      for (int ni = 0; ni < 4; ++ni)
        acc[mi][ni] = __builtin_amdgcn_mfma_f32_16x16x32_f16(
            af[mi], bfr[ni], acc[mi][ni], 0, 0, 0);

    __syncthreads();   // drains this iter's STAGE (vmcnt0) + read fences
  }
#undef STAGE
}

// block-index decode shared by both GEMM passes (XCD swizzle: 3200 blocks =
// 8 XCDs x 400 slots; mt fastest so B-tile siblings share an XCD L2).
__device__ __forceinline__ void decode_tile(int bid, int& mt, int& nt,
                                            int& b, int& s0)
{
  const int tile = (bid & 7) * 400 + (bid >> 3);
  mt = tile & 3;
  const int q2 = tile >> 2;
  nt = q2 % 25;
  b  = q2 / 25;
  s0 = (nt == 24) ? (HW - 128) : nt * 128;
}

// ---------------------------------------------------------------------------
// Pass 1: GEMM + per-group sum/sumsq only (no y). Bijective stats slot
// (b,g,nt,wx) written unconditionally -> deterministic, no init dependency.
// Edge tile nt==24 counts only its exclusive columns (>=3072).
// ---------------------------------------------------------------------------
__global__ __launch_bounds__(256) void k_gemm_stats(
    const _Float16* __restrict__ xT, const _Float16* __restrict__ wf,
    float2* __restrict__ stats)
{
  int mt, nt, b, s0;
  decode_tile(blockIdx.x, mt, nt, b, s0);

  const int t    = threadIdx.x;
  const int lane = t & 63;
  const int wid  = t >> 6;
  const int wy   = wid >> 1, wx = wid & 1;

  f32x4 acc[4][4] = {};
  gemm_tile(xT, wf, b, mt, s0, t, acc);

  const int slo  = (nt == 24) ? 3072 : 0;
  const int colb = s0 + wx * 64 + (lane & 15);
#pragma unroll
  for (int mi = 0; mi < 4; ++mi) {
    float s1 = 0.f, s2 = 0.f;
#pragma unroll
    for (int ni = 0; ni < 4; ++ni) {
      if (colb + ni * 16 >= slo) {
#pragma unroll
        for (int rr = 0; rr < 4; ++rr) {
          const float v = acc[mi][ni][rr];
          s1 += v; s2 += v * v;
        }
      }
    }
#pragma unroll
    for (int off = 32; off > 0; off >>= 1) {
      s1 += __shfl_down(s1, off, 64);
      s2 += __shfl_down(s2, off, 64);
    }
    if (lane == 0) {
      const int g = mt * 8 + wy * 4 + mi;   // group = one 16-row m-subtile
      stats[((b * NG + g) * 25 + nt) * 2 + wx] = make_float2(s1, s2);
    }
  }
}

// ---------------------------------------------------------------------------
// K2: per-(b,co) scale/shift: sc = rsig*gamma[co], sh = beta[co] - mean*sc.
// Sums the 50 partials per group in a fixed order — bit-deterministic.
// ---------------------------------------------------------------------------
__global__ __launch_bounds__(256) void k_finalize(
    const float2* __restrict__ stats, const float* __restrict__ gamma,
    const float* __restrict__ beta, float* __restrict__ ss)
{
  const int i = blockIdx.x * 256 + threadIdx.x;   // b*COUT + co
  if (i < BATCH * COUT) {
    const int b  = i >> 9;
    const int co = i & (COUT - 1);
    const int g  = co >> 4;
    const float2* sp = stats + (size_t)(b * NG + g) * 50;
    float s1 = 0.f, s2 = 0.f;
#pragma unroll 10
    for (int j = 0; j < 50; ++j) { s1 += sp[j].x; s2 += sp[j].y; }
    const float cnt  = (float)(CPG * HW);
    const float mean = s1 / cnt;
    const float var  = s2 / cnt - mean * mean;
    const float rsig = rsqrtf(var + EPS);
    const float sc   = rsig * gamma[co];
    ss[i * 2 + 0] = sc;
    ss[i * 2 + 1] = beta[co] - mean * sc;
  }
}

// ---------------------------------------------------------------------------
// Pass 2: GEMM recompute + normalize + HardTanh, direct f32 out stores.
// Same tile decode; exclusive writers via the slo predicate (edge tile
// nt==24 stores only s>=3072; overlap [3008,3072) owned by nt==23).
// Store pattern: 16 lanes x 4B = 64B segments; ni x 16 floats -> 256B
// contiguous per (mi,rr) output row.
// ---------------------------------------------------------------------------
__global__ __launch_bounds__(256) void k_gemm_out(
    const _Float16* __restrict__ xT, const _Float16* __restrict__ wf,
    const float* __restrict__ ss, float* __restrict__ out)
{
  int mt, nt, b, s0;
  decode_tile(blockIdx.x, mt, nt, b, s0);

  const int t    = threadIdx.x;
  const int lane = t & 63;
  const int wid  = t >> 6;
  const int wy   = wid >> 1, wx = wid & 1;

  f32x4 acc[4][4] = {};
  gemm_tile(xT, wf, b, mt, s0, t, acc);

  const int slo  = (nt == 24) ? 3072 : 0;
  const int colb = s0 + wx * 64 + (lane & 15);
#pragma unroll
  for (int mi = 0; mi < 4; ++mi) {
    const int row0 = mt * 128 + wy * 64 + mi * 16 + ((lane >> 4) << 2);
#pragma unroll
    for (int rr = 0; rr < 4; ++rr) {
      const int row = row0 + rr;
      const float2 sv = *(const float2*)(ss + (size_t)(b * COUT + row) * 2);
      float* orow = out + ((size_t)b * COUT + row) * HW + colb;
#pragma unroll
      for (int ni = 0; ni < 4; ++ni) {
        if (colb + ni * 16 >= slo) {
          const float v = acc[mi][ni][rr] * sv.x + sv.y;
          orow[ni * 16] = fminf(fmaxf(v, -2.0f), 2.0f);
        }
      }
    }
  }
}

extern "C" void kernel_launch(void* const* d_in, const int* in_sizes, int n_in,
                              void* d_out, int out_size, void* d_ws, size_t ws_size,
                              hipStream_t stream)
{
  const float* x     = (const float*)d_in[0];
  const float* w     = (const float*)d_in[1];
  const float* gamma = (const float*)d_in[2];
  const float* beta  = (const float*)d_in[3];
  float* out = (float*)d_out;

  const size_t xT_bytes = (size_t)BATCH * HW * CIN * 2;     // 51,380,224
  const size_t wf_bytes = (size_t)COUT * CIN * 2;           //    262,144
  const size_t st_bytes = (size_t)BATCH * NG * 50 * 8;      //    409,600
  const size_t ss_bytes = (size_t)BATCH * COUT * 2 * 4;     //    131,072

  char* ws = (char*)d_ws;
  _Float16* xT  = (_Float16*)ws;
  _Float16* wf  = (_Float16*)(ws + xT_bytes);
  float2*  stats = (float2*)(ws + xT_bytes + wf_bytes);
  float*   ss    = (float*)(ws + xT_bytes + wf_bytes + st_bytes);

  if (ws_size < xT_bytes + wf_bytes + st_bytes + ss_bytes) return;

  k0_transpose<<<dim3(BATCH * 196), dim3(256), 0, stream>>>(x, w, xT, wf);
  k_gemm_stats<<<dim3(BATCH * 100), dim3(256), 0, stream>>>(xT, wf, stats);
  k_finalize<<<dim3(BATCH * COUT / 256), dim3(256), 0, stream>>>(stats, gamma, beta, ss);
  k_gemm_out<<<dim3(BATCH * 100), dim3(256), 0, stream>>>(xT, wf, ss, out);
}

// Round 8
// 382.152 us; speedup vs baseline: 1.0132x; 1.0132x over previous
//
#include <hip/hip_runtime.h>

// Fused 1x1-conv GEMM + GroupNorm + HardTanh, MI355X (gfx950).
// Round 11: discriminating experiment. Measurements so far:
//   R4  (m97-core gemm, y f16, one-shot k_norm)          = 368.9us PASS
//   R9  (BK32 dbuf pipeline, NT k_norm)                  = 377.9us PASS
//   R10 (recompute, no y)                                = 387.2us PASS
// Solving the shared-component system: G_core = k_norm + e1 - e2 - 17us.
// Two self-consistent models: A) fills=244us in-graph, all kernels at
// floor (no headroom); B) fills=127us, k_norm ~105us (2.9TB/s, off its
// 49us floor) and gemm ~90us. This round: revert to the verbatim R4 gemm
// (best core) and change ONLY k_norm: grid-stride 2048 blocks (was 25088
// one-shot blocks) + nontemporal f32x4 out stores. Null result => Model A
// (composite floor) => next is 8-phase gemm port or roofline.

#define HW    3136
#define CIN   256
#define COUT  512
#define BATCH 32
#define NG    32
#define CPG   16
#define EPS   1e-5f

typedef _Float16 f16x8 __attribute__((ext_vector_type(8)));
typedef float    f32x4 __attribute__((ext_vector_type(4)));
typedef unsigned int u32;

// async global->LDS DMA, 16B per lane; LDS dest = wave-uniform base + lane*16
__device__ __forceinline__ void gload16(const void* g, void* l) {
  __builtin_amdgcn_global_load_lds(
      (const u32 __attribute__((address_space(1)))*)g,
      (u32 __attribute__((address_space(3)))*)l, 16, 0, 0);
}

// ---------------------------------------------------------------------------
// K0: x [B][CIN][HW] f32 -> xT [B][HW][CIN] f16. 64x64 tile via fp32 LDS,
// row stride 65 dwords => <=2-way bank aliasing both phases (free per m136).
// Also converts w->f16. Verbatim the round-4 passing kernel.
// ---------------------------------------------------------------------------
__global__ __launch_bounds__(256) void k0_transpose(
    const float* __restrict__ x, const float* __restrict__ w,
    _Float16* __restrict__ xT, _Float16* __restrict__ wf)
{
  __shared__ float T[64 * 65];
  const int bid = blockIdx.x;
  const int t   = threadIdx.x;
  const int b   = bid / 196;       // 49 s-tiles * 4 c-tiles
  const int r   = bid % 196;
  const int st  = r >> 2;
  const int ct  = r & 3;
  const int s0  = st * 64, c0 = ct * 64;

  const float* xb = x + ((size_t)b * CIN + c0) * HW + s0;
#pragma unroll
  for (int rr = 0; rr < 4; ++rr) {
    const int c_loc = (t >> 4) + rr * 16;
    const int s4    = (t & 15) * 4;
    const float4 v  = *(const float4*)(xb + (size_t)c_loc * HW + s4);
    T[(s4 + 0) * 65 + c_loc] = v.x;
    T[(s4 + 1) * 65 + c_loc] = v.y;
    T[(s4 + 2) * 65 + c_loc] = v.z;
    T[(s4 + 3) * 65 + c_loc] = v.w;
  }
  __syncthreads();
#pragma unroll
  for (int p = 0; p < 2; ++p) {
    const int s_loc = p * 32 + (t >> 3);
    const int cg    = (t & 7) * 8;
    f16x8 o;
#pragma unroll
    for (int j = 0; j < 8; ++j) o[j] = (_Float16)T[s_loc * 65 + cg + j];
    *(f16x8*)(xT + ((size_t)b * HW + s0 + s_loc) * CIN + c0 + cg) = o;
  }
  if (bid < (COUT * CIN) / 256) wf[bid * 256 + t] = (_Float16)w[bid * 256 + t];
}

// ---------------------------------------------------------------------------
// K1: GEMM C[128co x 128s]/block, BK=64, 4 waves (2x2), 4x4 16x16x32 f16
// MFMA tiles/wave. Verbatim the round-4 passing kernel (best measured core):
// barrier -> global_load_lds stage (global-side XOR chunk perm) -> barrier
// -> ds_read+MFMA. Epilogue: bijective stats partials + exclusive y f16.
// ---------------------------------------------------------------------------
__global__ __launch_bounds__(256) void k_gemm(
    const _Float16* __restrict__ xT, const _Float16* __restrict__ wf,
    float2* __restrict__ stats, _Float16* __restrict__ y)
{
  __shared__ __align__(16) _Float16 As[128 * 64];
  __shared__ __align__(16) _Float16 Bs[128 * 64];

  // XCD swizzle: 3200 blocks = 8 XCDs x 400 slots; mt fastest within an XCD
  // so the 4 mt-siblings sharing a B-tile hit the same XCD's L2.
  const int bid  = blockIdx.x;
  const int tile = (bid & 7) * 400 + (bid >> 3);
  const int mt   = tile & 3;
  const int q2   = tile >> 2;
  const int nt   = q2 % 25;
  const int b    = q2 / 25;
  const int s0   = (nt == 24) ? (HW - 128) : nt * 128;

  const int t    = threadIdx.x;
  const int lane = t & 63;
  const int wid  = t >> 6;
  const int wy   = wid >> 1, wx = wid & 1;
  const int lr   = lane >> 3;          // LDS row-within-8 this lane fills
  const int ccg  = (lane & 7) ^ lr;    // global-side chunk permutation

  f32x4 acc[4][4] = {};
  const _Float16* xb = xT + (size_t)b * HW * CIN;

  for (int kt = 0; kt < 4; ++kt) {
    __syncthreads();
    const int ko = kt * 64;
#pragma unroll
    for (int u = 0; u < 4; ++u) {
      const int rowb = (wid * 4 + u) * 8 + lr;
      gload16(wf + (size_t)(mt * 128 + rowb) * CIN + ko + ccg * 8,
              As + (wid * 4 + u) * 512);
      gload16(xb + (size_t)(s0 + rowb) * CIN + ko + ccg * 8,
              Bs + (wid * 4 + u) * 512);
    }
    __syncthreads();
#pragma unroll
    for (int ks = 0; ks < 2; ++ks) {
      const int c = ks * 4 + (lane >> 4);
      f16x8 af[4], bfr[4];
#pragma unroll
      for (int mi = 0; mi < 4; ++mi) {
        const int m = wy * 64 + mi * 16 + (lane & 15);
        af[mi] = *(const f16x8*)(As + m * 64 + ((c ^ (m & 7)) * 8));
      }
#pragma unroll
      for (int ni = 0; ni < 4; ++ni) {
        const int n = wx * 64 + ni * 16 + (lane & 15);
        bfr[ni] = *(const f16x8*)(Bs + n * 64 + ((c ^ (n & 7)) * 8));
      }
#pragma unroll
      for (int mi = 0; mi < 4; ++mi)
#pragma unroll
        for (int ni = 0; ni < 4; ++ni)
          acc[mi][ni] = __builtin_amdgcn_mfma_f32_16x16x32_f16(
              af[mi], bfr[ni], acc[mi][ni], 0, 0, 0);
    }
  }

  // ---- epilogue: deterministic partial stats + exclusive y f16 store ----
  const int slo  = (nt == 24) ? 3072 : 0;   // exclusive-ownership threshold
  const int colb = s0 + wx * 64 + (lane & 15);
#pragma unroll
  for (int mi = 0; mi < 4; ++mi) {
    float s1 = 0.f, s2 = 0.f;
#pragma unroll
    for (int ni = 0; ni < 4; ++ni) {
      if (colb + ni * 16 >= slo) {
#pragma unroll
        for (int rr = 0; rr < 4; ++rr) {
          const float v = acc[mi][ni][rr];
          s1 += v; s2 += v * v;
        }
      }
    }
#pragma unroll
    for (int off = 32; off > 0; off >>= 1) {
      s1 += __shfl_down(s1, off, 64);
      s2 += __shfl_down(s2, off, 64);
    }
    if (lane == 0) {
      // bijective slot: (b, g, nt, wx) — 51,200 stores onto 51,200 slots,
      // written unconditionally every launch (nt==24/wx==0 writes zeros).
      const int g = mt * 8 + wy * 4 + mi;
      stats[((b * NG + g) * 25 + nt) * 2 + wx] = make_float2(s1, s2);
    }
    // y store: 4 rows x 4 col-tiles of f16 scalars; L2 merges the 32B
    // segments into full lines. Predicated so the overlap columns
    // [3008,3072) are written only by the nt==23 block (single writer).
    const int row0 = mt * 128 + wy * 64 + mi * 16 + ((lane >> 4) << 2);
#pragma unroll
    for (int rr = 0; rr < 4; ++rr) {
      _Float16* yrow = y + ((size_t)b * COUT + row0 + rr) * HW + colb;
#pragma unroll
      for (int ni = 0; ni < 4; ++ni)
        if (colb + ni * 16 >= slo) yrow[ni * 16] = (_Float16)acc[mi][ni][rr];
    }
  }
}

// ---------------------------------------------------------------------------
// K2: per-(b,co) scale/shift: sc = rsig*gamma[co], sh = beta[co] - mean*sc.
// Sums the 50 partials per group in a fixed order — bit-deterministic.
// ---------------------------------------------------------------------------
__global__ __launch_bounds__(256) void k_finalize(
    const float2* __restrict__ stats, const float* __restrict__ gamma,
    const float* __restrict__ beta, float* __restrict__ ss)
{
  const int i = blockIdx.x * 256 + threadIdx.x;   // b*COUT + co
  if (i < BATCH * COUT) {
    const int b  = i >> 9;
    const int co = i & (COUT - 1);
    const int g  = co >> 4;
    const float2* sp = stats + (size_t)(b * NG + g) * 50;
    float s1 = 0.f, s2 = 0.f;
#pragma unroll 10
    for (int j = 0; j < 50; ++j) { s1 += sp[j].x; s2 += sp[j].y; }
    const float cnt  = (float)(CPG * HW);
    const float mean = s1 / cnt;
    const float var  = s2 / cnt - mean * mean;
    const float rsig = rsqrtf(var + EPS);
    const float sc   = rsig * gamma[co];
    ss[i * 2 + 0] = sc;
    ss[i * 2 + 1] = beta[co] - mean * sc;
  }
}

// ---------------------------------------------------------------------------
// K3: streaming normalize + HardTanh. y f16 [B][COUT][HW] -> out f32.
// CHANGED this round: grid-stride over 2048 blocks (was 25088 one-shot
// blocks) per memory-bound guideline 11, nontemporal f32x4 out stores
// (write-once stream; keep L2/L3 for the y reads). 8 elems/iter/thread,
// fully coalesced 16B read + 2x16B write.
// ---------------------------------------------------------------------------
#define NORM_BLOCKS 2048
__global__ __launch_bounds__(256) void k_norm(
    const _Float16* __restrict__ y, const float* __restrict__ ss,
    float* __restrict__ out)
{
  const u32 total = (u32)BATCH * COUT * (HW / 8);          // 8-elem units
  for (u32 u = blockIdx.x * 256 + threadIdx.x; u < total;
       u += (u32)NORM_BLOCKS * 256) {
    const u32 row = u / (HW / 8);                          // b*COUT + co
    const u32 sp  = (u - row * (HW / 8)) * 8;
    const float sc = ss[row * 2 + 0];
    const float sh = ss[row * 2 + 1];
    const f16x8 v = *(const f16x8*)(y + (size_t)row * HW + sp);
    f32x4 o0, o1;
    o0[0] = fminf(fmaxf((float)v[0] * sc + sh, -2.0f), 2.0f);
    o0[1] = fminf(fmaxf((float)v[1] * sc + sh, -2.0f), 2.0f);
    o0[2] = fminf(fmaxf((float)v[2] * sc + sh, -2.0f), 2.0f);
    o0[3] = fminf(fmaxf((float)v[3] * sc + sh, -2.0f), 2.0f);
    o1[0] = fminf(fmaxf((float)v[4] * sc + sh, -2.0f), 2.0f);
    o1[1] = fminf(fmaxf((float)v[5] * sc + sh, -2.0f), 2.0f);
    o1[2] = fminf(fmaxf((float)v[6] * sc + sh, -2.0f), 2.0f);
    o1[3] = fminf(fmaxf((float)v[7] * sc + sh, -2.0f), 2.0f);
    float* op = out + (size_t)row * HW + sp;
    __builtin_nontemporal_store(o0, (f32x4*)(op));
    __builtin_nontemporal_store(o1, (f32x4*)(op + 4));
  }
}

extern "C" void kernel_launch(void* const* d_in, const int* in_sizes, int n_in,
                              void* d_out, int out_size, void* d_ws, size_t ws_size,
                              hipStream_t stream)
{
  const float* x     = (const float*)d_in[0];
  const float* w     = (const float*)d_in[1];
  const float* gamma = (const float*)d_in[2];
  const float* beta  = (const float*)d_in[3];
  float* out = (float*)d_out;

  const size_t xT_bytes = (size_t)BATCH * HW * CIN * 2;     // 51,380,224
  const size_t wf_bytes = (size_t)COUT * CIN * 2;           //    262,144
  const size_t st_bytes = (size_t)BATCH * NG * 50 * 8;      //    409,600
  const size_t ss_bytes = (size_t)BATCH * COUT * 2 * 4;     //    131,072
  const size_t y_bytes  = (size_t)BATCH * COUT * HW * 2;    // 102,760,448

  char* ws = (char*)d_ws;
  _Float16* xT = (_Float16*)ws;
  _Float16* wf = (_Float16*)(ws + xT_bytes);
  float2* stats = (float2*)(ws + xT_bytes + wf_bytes);
  float* ss    = (float*)(ws + xT_bytes + wf_bytes + st_bytes);
  _Float16* y  = (_Float16*)(ws + xT_bytes + wf_bytes + st_bytes + ss_bytes);

  if (ws_size < xT_bytes + wf_bytes + st_bytes + ss_bytes + y_bytes) return;

  k0_transpose<<<dim3(BATCH * 196), dim3(256), 0, stream>>>(x, w, xT, wf);
  k_gemm<<<dim3(BATCH * 100), dim3(256), 0, stream>>>(xT, wf, stats, y);
  k_finalize<<<dim3(BATCH * COUT / 256), dim3(256), 0, stream>>>(stats, gamma, beta, ss);
  k_norm<<<dim3(NORM_BLOCKS), dim3(256), 0, stream>>>(y, ss, out);
}